// Round 7
// baseline (621.792 us; speedup 1.0000x reference)
//
#include <hip/hip_runtime.h>
#include <hip/hip_bf16.h>
#include <math.h>

#define N_NODES 50000
#define E0      800000
#define E_TOT   (E0 + N_NODES)

using bf16 = __hip_bfloat16;

// ---------------- dtype autodetect ----------------
// flag[0]=1 -> edges int32 ; flag[1]=1 -> float tensors are fp32
__global__ void k_detect(const int* __restrict__ ei, const unsigned* __restrict__ xu,
                         int* __restrict__ flag){
    __shared__ int e32, f32;
    if (threadIdx.x == 0){ e32 = 0; f32 = 0; }
    __syncthreads();
    if (ei[2 * threadIdx.x + 1] != 0) e32 = 1;        // int64 high words are 0
    if (threadIdx.x < 128){
        unsigned ex = (xu[threadIdx.x] >> 7) & 0xFF;  // bf16 exponent of low halfword
        if (ex < 100 || ex > 140) f32 = 1;            // fp32 mantissa bits look random
    }
    __syncthreads();
    if (threadIdx.x == 0){ flag[0] = e32; flag[1] = f32; }
}

static __device__ __forceinline__ float ldany(const void* p, int i, int isf32){
    return isf32 ? ((const float*)p)[i] : __bfloat162float(((const bf16*)p)[i]);
}

// vecf layout: b1 @0(128), bg @128(64), b3 @192(64), att_s @256(128), att_d @384(128)
__global__ void k_convert(const int* __restrict__ flag,
                          const void* W1, const void* Wg, const void* W3,
                          const void* b1, const void* bg, const void* b3,
                          const void* as_, const void* ad_,
                          float* __restrict__ W1f, float* __restrict__ Wgf,
                          float* __restrict__ W3f, float* __restrict__ vecf){
    int isf = flag[1];
    int b = blockIdx.x, t = threadIdx.x;
    if (b < 64){                 int i = b * 256 + t;         W1f[i] = ldany(W1, i, isf); }
    else if (b < 128){           int i = (b - 64) * 256 + t;  Wgf[i] = ldany(Wg, i, isf); }
    else if (b < 144){           int i = (b - 128) * 256 + t; W3f[i] = ldany(W3, i, isf); }
    else {
        int i = (b - 144) * 256 + t;     // 0..511
        float v;
        if      (i < 128) v = ldany(b1,  i,       isf);
        else if (i < 192) v = ldany(bg,  i - 128, isf);
        else if (i < 256) v = ldany(b3,  i - 192, isf);
        else if (i < 384) v = ldany(as_, i - 256, isf);
        else              v = ldany(ad_, i - 384, isf);
        vecf[i] = v;
    }
}

// x (N,128) -> bf16 copy
__global__ void k_convx(const void* __restrict__ xv, const int* __restrict__ flag,
                        bf16* __restrict__ xb){
    int i = blockIdx.x * 256 + threadIdx.x;
    if (i >= N_NODES * 128) return;
    xb[i] = __float2bfloat16(ldany(xv, i, flag[1]));
}

// ---------------- CSR build ----------------

__global__ void k_zero2(int* p0, int* p1, int n){
    int i = blockIdx.x * blockDim.x + threadIdx.x;
    if (i < n){ p0[i] = 0; p1[i] = 0; }
}

static __device__ __forceinline__ int load_dst(const int* ei, int e, int is32){
    if (e >= E0) return e - E0;
    return is32 ? ei[E0 + e] : (int)((const long long*)ei)[E0 + e];
}
static __device__ __forceinline__ int load_src(const int* ei, int e, int is32){
    if (e >= E0) return e - E0;
    return is32 ? ei[e] : (int)((const long long*)ei)[e];
}

__global__ void k_count(const int* __restrict__ ei, const int* __restrict__ flag,
                        int* __restrict__ deg){
    int e = blockIdx.x * blockDim.x + threadIdx.x;
    if (e >= E_TOT) return;
    int is32 = flag[0];
    int dst = load_dst(ei, e, is32);
    int src = load_src(ei, e, is32);
    if ((unsigned)dst >= N_NODES || (unsigned)src >= N_NODES) return;
    atomicAdd(&deg[dst], 1);
}

__global__ void k_scanA(const int* __restrict__ deg, int* __restrict__ tmp, int* __restrict__ blk){
    __shared__ int s[256];
    int t = threadIdx.x;
    int i = blockIdx.x * 256 + t;
    int v = (i < N_NODES) ? deg[i] : 0;
    s[t] = v; __syncthreads();
    for (int off = 1; off < 256; off <<= 1){
        int x = (t >= off) ? s[t - off] : 0;
        __syncthreads();
        s[t] += x;
        __syncthreads();
    }
    if (t == 255) blk[blockIdx.x] = s[255];
    if (i < N_NODES) tmp[i] = s[t] - v;
}

__global__ void k_scanB(int* __restrict__ blk, int nb){
    __shared__ int s[256];
    int t = threadIdx.x;
    int v = (t < nb) ? blk[t] : 0;
    s[t] = v; __syncthreads();
    for (int off = 1; off < 256; off <<= 1){
        int x = (t >= off) ? s[t - off] : 0;
        __syncthreads();
        s[t] += x;
        __syncthreads();
    }
    if (t < nb) blk[t] = s[t] - v;
}

__global__ void k_scanC(int* __restrict__ row_ptr, const int* __restrict__ blk,
                        const int* __restrict__ deg, float* __restrict__ inv_sqrt){
    int i = blockIdx.x * blockDim.x + threadIdx.x;
    if (i < N_NODES){
        row_ptr[i] += blk[i >> 8];
        int d = deg[i];
        inv_sqrt[i] = (d > 0) ? rsqrtf((float)d) : 0.0f;
    }
    if (i == 0) row_ptr[N_NODES] = E_TOT;
}

// also writes coef[pos] = isq[dst]*isq[src] (kills dependent isq load in gathers)
__global__ void k_fill(const int* __restrict__ ei, const int* __restrict__ flag,
                       const int* __restrict__ row_ptr, const float* __restrict__ isq,
                       int* __restrict__ cursor, int* __restrict__ csr_src,
                       float* __restrict__ coef){
    int e = blockIdx.x * blockDim.x + threadIdx.x;
    if (e >= E_TOT) return;
    int is32 = flag[0];
    int dst = load_dst(ei, e, is32);
    int src = load_src(ei, e, is32);
    if ((unsigned)dst >= N_NODES || (unsigned)src >= N_NODES) return;
    int pos = row_ptr[dst] + atomicAdd(&cursor[dst], 1);
    csr_src[pos] = src;
    coef[pos] = isq[dst] * isq[src];
}

// ---------------- mega1: gather(xb) -> GEMM1+ReLU -> GEMM2 -> att logits ----------------
// 128 threads/block, 8 nodes/block. Thread j owns feature column j.
// X2 stored interleaved: row n, bf16 slot (f*2 + head) so k_gat reads one u32/lane.
__global__ __launch_bounds__(128) void k_mega1(
        const bf16* __restrict__ xb, const int* __restrict__ rp,
        const int* __restrict__ csr, const float* __restrict__ cf,
        const float* __restrict__ W1f, const float* __restrict__ Wgf,
        const float* __restrict__ vecf,
        bf16* __restrict__ X2, float* __restrict__ a_src, float* __restrict__ a_dst){
    __shared__ float as[8][128];
    __shared__ float hs[8][128];
    int n0 = blockIdx.x * 8;
    int j = threadIdx.x;

    // gather A_hat x rows (precomputed coef; uniform-addr csr/cf loads)
    #pragma unroll 2
    for (int r = 0; r < 8; ++r){
        int n = n0 + r;
        float a = 0.f;
        int b = rp[n], e = rp[n + 1];
        for (int i = b; i < e; ++i){
            int s = csr[i];
            a += cf[i] * __bfloat162float(xb[(size_t)s * 128 + j]);
        }
        as[r][j] = a;
    }
    __syncthreads();

    // GEMM1 + b1 + ReLU (float4 LDS reads, k unroll 4)
    {
        float acc[8] = {0.f,0.f,0.f,0.f,0.f,0.f,0.f,0.f};
        for (int k = 0; k < 128; k += 4){
            float w0 = W1f[k * 128 + j],       w1 = W1f[(k + 1) * 128 + j];
            float w2 = W1f[(k + 2) * 128 + j], w3 = W1f[(k + 3) * 128 + j];
            #pragma unroll
            for (int r = 0; r < 8; ++r){
                float4 av = *(const float4*)&as[r][k];
                acc[r] += av.x * w0 + av.y * w1 + av.z * w2 + av.w * w3;
            }
        }
        float bb = vecf[j];   // b1
        #pragma unroll
        for (int r = 0; r < 8; ++r) hs[r][j] = fmaxf(acc[r] + bb, 0.f);
    }
    __syncthreads();

    // GEMM2 (h2 = h @ Wg) + att logits from fp32 + interleaved bf16 store
    float acc2[8] = {0.f,0.f,0.f,0.f,0.f,0.f,0.f,0.f};
    for (int k = 0; k < 128; k += 4){
        float w0 = Wgf[k * 128 + j],       w1 = Wgf[(k + 1) * 128 + j];
        float w2 = Wgf[(k + 2) * 128 + j], w3 = Wgf[(k + 3) * 128 + j];
        #pragma unroll
        for (int r = 0; r < 8; ++r){
            float4 av = *(const float4*)&hs[r][k];
            acc2[r] += av.x * w0 + av.y * w1 + av.z * w2 + av.w * w3;
        }
    }
    float asv = vecf[256 + j], adv = vecf[384 + j];  // att_src, att_dst (head-major)
    int f = j & 63, h = j >> 6;
    #pragma unroll
    for (int r = 0; r < 8; ++r){
        int n = n0 + r;
        X2[(size_t)n * 128 + f * 2 + h] = __float2bfloat16(acc2[r]);
        float ps = acc2[r] * asv, pd = acc2[r] * adv;
        for (int off = 32; off; off >>= 1){
            ps += __shfl_down(ps, off, 64);
            pd += __shfl_down(pd, off, 64);
        }
        if (f == 0){
            a_src[n * 2 + h] = ps;
            a_dst[n * 2 + h] = pd;
        }
    }
}

// ---------------- GAT aggregate: softmax (no-max; logits bounded) + mean + bg + ELU ----
__global__ __launch_bounds__(256) void k_gat(
        const unsigned* __restrict__ X2u, const int* __restrict__ rp,
        const int* __restrict__ csr, const float2* __restrict__ a_src,
        const float2* __restrict__ a_dst, const float* __restrict__ vecf,
        bf16* __restrict__ Y){
    int n = blockIdx.x * 4 + (threadIdx.x >> 6);
    int f = threadIdx.x & 63;
    float2 ad = a_dst[n];
    float l0 = 0.f, l1 = 0.f, o0 = 0.f, o1 = 0.f;
    int b = rp[n], e = rp[n + 1];
    for (int i = b; i < e; ++i){
        int s = csr[i];
        float2 av = a_src[s];
        unsigned v = X2u[(size_t)s * 64 + f];          // both heads, one 4B load
        float e0 = av.x + ad.x, e1 = av.y + ad.y;
        e0 = (e0 > 0.f) ? e0 : 0.2f * e0;              // leaky_relu 0.2
        e1 = (e1 > 0.f) ? e1 : 0.2f * e1;
        float p0 = __expf(e0), p1 = __expf(e1);
        float x0 = __uint_as_float(v << 16);           // head0 (bf16 low half)
        float x1 = __uint_as_float(v & 0xffff0000u);   // head1 (bf16 high half)
        l0 += p0;  o0 += p0 * x0;
        l1 += p1;  o1 += p1 * x1;
    }
    float val = 0.5f * (o0 / l0 + o1 / l1) + vecf[128 + f];  // bg (self-loop => l>0)
    val = (val > 0.f) ? val : expm1f(val);                    // ELU alpha=1
    Y[(size_t)n * 64 + f] = __float2bfloat16(val);
}

// ---------------- mega3: gather(Y bf16) + W3 GEMM (W3 in LDS) -> out ----------------
__global__ __launch_bounds__(256) void k_mega3(
        const bf16* __restrict__ Yb, const int* __restrict__ rp,
        const int* __restrict__ csr, const float* __restrict__ cf,
        const float* __restrict__ W3f, const float* __restrict__ vecf,
        float* __restrict__ out){
    __shared__ float w3s[4096];
    __shared__ float rows[4][64];
    for (int i = threadIdx.x; i < 4096; i += 256) w3s[i] = W3f[i];
    int w = threadIdx.x >> 6, f = threadIdx.x & 63;
    int n = blockIdx.x * 4 + w;
    float a = 0.f;
    int b = rp[n], e = rp[n + 1];
    for (int i = b; i < e; ++i){
        int s = csr[i];
        a += cf[i] * __bfloat162float(Yb[(size_t)s * 64 + f]);
    }
    rows[w][f] = a;
    __syncthreads();
    float acc = vecf[192 + f];                 // b3
    for (int k = 0; k < 64; k += 4){
        float4 rv = *(const float4*)&rows[w][k];
        acc += rv.x * w3s[k * 64 + f]       + rv.y * w3s[(k + 1) * 64 + f]
             + rv.z * w3s[(k + 2) * 64 + f] + rv.w * w3s[(k + 3) * 64 + f];
    }
    out[(size_t)n * 64 + f] = acc;
}

// ---------------- launch ----------------

extern "C" void kernel_launch(void* const* d_in, const int* in_sizes, int n_in,
                              void* d_out, int out_size, void* d_ws, size_t ws_size,
                              hipStream_t stream) {
    const void* x  = d_in[0];
    const int*  ei = (const int*)d_in[1];
    float* out = (float*)d_out;

    char* p = (char*)d_ws;
    auto alloc = [&](size_t bytes) -> void* {
        void* r = (void*)p;
        p += (bytes + 255) & ~(size_t)255;
        return r;
    };
    int*   flag     = (int*)  alloc(8);
    int*   deg      = (int*)  alloc((size_t)N_NODES * 4);
    int*   cursor   = (int*)  alloc((size_t)N_NODES * 4);
    int*   row_ptr  = (int*)  alloc((size_t)(N_NODES + 1) * 4);
    int*   blk      = (int*)  alloc(256 * 4);
    int*   csr      = (int*)  alloc((size_t)E_TOT * 4);
    float* coef     = (float*)alloc((size_t)E_TOT * 4);
    float* inv_sqrt = (float*)alloc((size_t)N_NODES * 4);
    float* a_src    = (float*)alloc((size_t)N_NODES * 2 * 4);
    float* a_dst    = (float*)alloc((size_t)N_NODES * 2 * 4);
    float* W1f      = (float*)alloc(16384 * 4);
    float* Wgf      = (float*)alloc(16384 * 4);
    float* W3f      = (float*)alloc(4096 * 4);
    float* vecf     = (float*)alloc(512 * 4);
    bf16*  xb       = (bf16*) alloc((size_t)N_NODES * 128 * 2);  // 12.8 MB
    bf16*  X2       = (bf16*) alloc((size_t)N_NODES * 128 * 2);  // 12.8 MB (interleaved)
    bf16*  Y        = (bf16*) alloc((size_t)N_NODES * 64 * 2);   //  6.4 MB
    // total ~41 MB

    const int NB_NODE = (N_NODES + 255) / 256;
    const int NB_EDGE = (E_TOT + 255) / 256;

    k_detect<<<1, 256, 0, stream>>>(ei, (const unsigned*)x, flag);
    k_convert<<<146, 256, 0, stream>>>(flag, d_in[2], d_in[4], d_in[8],
                                       d_in[3], d_in[7], d_in[9], d_in[5], d_in[6],
                                       W1f, Wgf, W3f, vecf);
    k_convx<<<(N_NODES * 128 + 255) / 256, 256, 0, stream>>>(x, flag, xb);

    k_zero2<<<NB_NODE, 256, 0, stream>>>(deg, cursor, N_NODES);
    k_count<<<NB_EDGE, 256, 0, stream>>>(ei, flag, deg);
    k_scanA<<<NB_NODE, 256, 0, stream>>>(deg, row_ptr, blk);
    k_scanB<<<1, 256, 0, stream>>>(blk, NB_NODE);
    k_scanC<<<NB_NODE, 256, 0, stream>>>(row_ptr, blk, deg, inv_sqrt);
    k_fill<<<NB_EDGE, 256, 0, stream>>>(ei, flag, row_ptr, inv_sqrt, cursor, csr, coef);

    k_mega1<<<N_NODES / 8, 128, 0, stream>>>(xb, row_ptr, csr, coef, W1f, Wgf, vecf,
                                             X2, a_src, a_dst);
    k_gat<<<N_NODES / 4, 256, 0, stream>>>((const unsigned*)X2, row_ptr, csr,
                                           (const float2*)a_src, (const float2*)a_dst,
                                           vecf, Y);
    k_mega3<<<N_NODES / 4, 256, 0, stream>>>(Y, row_ptr, csr, coef, W3f, vecf, out);
}